// Round 1
// 97.378 us; speedup vs baseline: 1.0125x; 1.0125x over previous
//
#include <hip/hip_runtime.h>
#include <math.h>

// B=8, H=32, W=32, C=512 -> HW=1024. Algebraic collapse of the reference:
//   rep[b,i] = pos_const * (x[b,i]·u_b + const_b);  min-max norm kills both consts.
//   y_b  = xsumtot - xsum_b
//   t1_b = conv_w·y_b + y_b + 7168*conv_b
//   t2_b = k_w·t1_b + 7168*k_b
//   w_b  = q_w^T·t2_b          (column-coalesced reads -> no transpose kernel)
//   u_b  = conv_w^T·w_b + w_b
//   d[b,i] = x[b,i]·u_b  -> per-batch min-max -> sigmoid((.-0.65)/0.15)
//
// Cost model (R1-R6): harness floor ~85 us (43 us ws-poison fill + restores +
// replay overhead); per-node gap ~0.65 us; every node is latency- or
// HBM-floor-bound -> the lever is NODE COUNT. This round: channel-split
// k_xsum produces xsum[8][512] directly (no partials, no atomics, no k_red)
// -> 7 nodes. Lessons kept: no device-scope fences (R3: 53 us cliff); no
// block-redundant MB reads per CU; small grids are latency cliffs (R1).

#define BATCH 8
#define HW    1024
#define CH    512
#define SPLITS 64

__device__ __forceinline__ float dot4(float4 a, float4 b) {
    return a.x * b.x + a.y * b.y + a.z * b.z + a.w * b.w;
}

// -------- K1: per-batch channel sums, channel-split (128 blocks x 512 thr) ----
// block = (b, 32-channel chunk); sums all 1024 rows for its chunk -> xsum direct.
// Wave access: 8 rows x 128 B aligned segments, 16 independent f4 loads/thread.
__global__ void k_xsum(const float* __restrict__ x, float* __restrict__ xsum) {
    int b = blockIdx.x >> 4, chunk = blockIdx.x & 15;   // 16 chunks of 32 ch
    int t = threadIdx.x;
    int col4 = t & 7, rg = t >> 3;                      // 64 row-groups x 8 f4-cols
    const float4* x4 = (const float4*)(x + (size_t)b * HW * CH) + chunk * 8 + col4;
    float4 acc; acc.x = acc.y = acc.z = acc.w = 0.f;
    #pragma unroll
    for (int i = 0; i < 16; ++i) {                      // rows rg, rg+64, ... rg+960
        float4 v = x4[(size_t)(rg + (i << 6)) * 128];
        acc.x += v.x; acc.y += v.y; acc.z += v.z; acc.w += v.w;
    }
    __shared__ float4 sh[64][8];
    sh[rg][col4] = acc;
    __syncthreads();
    if (t < 64) {                                       // 8 segs x 8 cols
        int c4 = t & 7, seg = t >> 3;
        float4 a = sh[seg * 8][c4];
        #pragma unroll
        for (int j = 1; j < 8; ++j) {
            float4 v = sh[seg * 8 + j][c4];
            a.x += v.x; a.y += v.y; a.z += v.z; a.w += v.w;
        }
        sh[seg][c4] = a;   // in-place: each cell read+written by the same thread only
    }
    __syncthreads();
    if (t < 8) {
        float4 a = sh[0][t];
        #pragma unroll
        for (int j = 1; j < 8; ++j) {
            float4 v = sh[j][t];
            a.x += v.x; a.y += v.y; a.z += v.z; a.w += v.w;
        }
        ((float4*)xsum)[b * 128 + chunk * 8 + t] = a;
    }
}

// -------- K2: t1[b][o] = conv_w[o]·y_b + y_b[o] + 7168*conv_b[o] ----------
// grid 1024 (128 blocks/batch, 4 wave-outputs each). y built per-block from xsum
// with float4 prelude (128 threads x 8 f4 loads).
__global__ void k_t1(const float* __restrict__ xsum, const float* __restrict__ conv_w,
                     const float* __restrict__ conv_b, float* __restrict__ t1g) {
    int t = threadIdx.x;
    int b = blockIdx.x >> 7;
    int wv = t >> 6, lane = t & 63;
    __shared__ float4 ysh[128];
    if (t < 128) {
        const float4* xs4 = (const float4*)xsum;
        float4 tot; tot.x = tot.y = tot.z = tot.w = 0.f;
        float4 own; own.x = own.y = own.z = own.w = 0.f;
        #pragma unroll
        for (int bb = 0; bb < BATCH; ++bb) {
            float4 v = xs4[bb * 128 + t];
            tot.x += v.x; tot.y += v.y; tot.z += v.z; tot.w += v.w;
            if (bb == b) own = v;
        }
        float4 y; y.x = tot.x - own.x; y.y = tot.y - own.y;
        y.z = tot.z - own.z; y.w = tot.w - own.w;
        ysh[t] = y;
    }
    __syncthreads();
    float4 ya = ysh[lane], yb = ysh[lane + 64];
    int o = (blockIdx.x & 127) * 4 + wv;
    const float4* w4 = (const float4*)(conv_w + (size_t)o * CH);
    float acc = dot4(ya, w4[lane]) + dot4(yb, w4[lane + 64]);
    #pragma unroll
    for (int off = 32; off; off >>= 1) acc += __shfl_xor(acc, off);
    if (lane == 0) t1g[b * CH + o] = acc + ((const float*)ysh)[o] + 7168.f * conv_b[o];
}

// -------- K3: t2[b][o] = k_w[o]·t1_b + 7168*k_b[o]  (grid 1024) --------
__global__ void k_t2(const float* __restrict__ t1g, const float* __restrict__ k_w,
                     const float* __restrict__ k_b, float* __restrict__ t2g) {
    int t = threadIdx.x;
    int b = blockIdx.x >> 7;
    int wv = t >> 6, lane = t & 63;
    __shared__ float4 ash[128];
    if (t < 128) ash[t] = ((const float4*)(t1g + b * CH))[t];
    __syncthreads();
    float4 aa = ash[lane], ab = ash[lane + 64];
    int o = (blockIdx.x & 127) * 4 + wv;
    const float4* w4 = (const float4*)(k_w + (size_t)o * CH);
    float acc = dot4(aa, w4[lane]) + dot4(ab, w4[lane + 64]);
    #pragma unroll
    for (int off = 32; off; off >>= 1) acc += __shfl_xor(acc, off);
    if (lane == 0) t2g[b * CH + o] = acc + 7168.f * k_b[o];
}

// -------- K4: w[b][c] = q_w^T[c]·t2_b  (column-coalesced; grid 64, 512 thr) --------
__global__ void k_wv(const float* __restrict__ t2g, const float* __restrict__ q_w,
                     float* __restrict__ wg) {
    int b = blockIdx.x >> 3, qc = blockIdx.x & 7;
    int t = threadIdx.x;
    __shared__ float t2sh[CH];
    __shared__ float ps[512];
    t2sh[t] = t2g[b * CH + t];
    __syncthreads();
    int c = qc * 64 + (t & 63), r0 = (t >> 6) * 64;
    float acc = 0.f;
    #pragma unroll 8
    for (int j = 0; j < 64; ++j) acc += q_w[(size_t)(r0 + j) * CH + c] * t2sh[r0 + j];
    ps[t] = acc;
    __syncthreads();
    if (t < 64) {
        float s = 0.f;
        #pragma unroll
        for (int k2 = 0; k2 < 8; ++k2) s += ps[k2 * 64 + t];
        wg[b * CH + qc * 64 + t] = s;
    }
}

// -------- K5: u[b][c] = conv_w^T[c]·w_b + w_b[c]  (grid 64, 512 thr) --------
__global__ void k_uv(const float* __restrict__ wg, const float* __restrict__ conv_w,
                     float* __restrict__ u) {
    int b = blockIdx.x >> 3, qc = blockIdx.x & 7;
    int t = threadIdx.x;
    __shared__ float wsh[CH];
    __shared__ float ps[512];
    wsh[t] = wg[b * CH + t];
    __syncthreads();
    int c = qc * 64 + (t & 63), r0 = (t >> 6) * 64;
    float acc = 0.f;
    #pragma unroll 8
    for (int j = 0; j < 64; ++j) acc += conv_w[(size_t)(r0 + j) * CH + c] * wsh[r0 + j];
    ps[t] = acc;
    __syncthreads();
    if (t < 64) {
        float s = 0.f;
        #pragma unroll
        for (int k2 = 0; k2 < 8; ++k2) s += ps[k2 * 64 + t];
        u[b * CH + qc * 64 + t] = s + wsh[qc * 64 + t];
    }
}

// -------- K6: d[b,p] = x[b,p]·u_b + per-block min/max (grid (64,8)) --------
__global__ void k_dpass(const float* __restrict__ x, const float* __restrict__ u,
                        float* __restrict__ dvals, float* __restrict__ bmn,
                        float* __restrict__ bmx) {
    int s = blockIdx.x, b = blockIdx.y;
    int lane = threadIdx.x & 63, wv = threadIdx.x >> 6;
    const float4* u4 = (const float4*)(u + b * CH);
    float4 ua = u4[lane], ub = u4[lane + 64];
    __shared__ float sd[16];
    #pragma unroll
    for (int it = 0; it < 4; ++it) {
        int row = s * 16 + it * 4 + wv;
        const float4* x4 = (const float4*)(x + ((size_t)(b * HW + row)) * CH);
        float acc = dot4(x4[lane], ua) + dot4(x4[lane + 64], ub);
        #pragma unroll
        for (int off = 32; off; off >>= 1) acc += __shfl_xor(acc, off);
        if (lane == 0) {
            dvals[b * HW + row] = acc;
            sd[it * 4 + wv] = acc;
        }
    }
    __syncthreads();
    if (threadIdx.x == 0) {
        float mn = sd[0], mx = sd[0];
        #pragma unroll
        for (int i = 1; i < 16; ++i) {
            mn = fminf(mn, sd[i]); mx = fmaxf(mx, sd[i]);
        }
        bmn[b * SPLITS + s] = mn;
        bmx[b * SPLITS + s] = mx;
    }
}

// -------- K7: min-max normalize + sigmoid (64 blocks x 128 thr) --------
// Widened from 8 blocks: one wave reduces the 64 split-min/max, then each of
// 128 threads emits exactly one output element (chunk of 128 per block).
__global__ void k_out(const float* __restrict__ dvals, const float* __restrict__ bmn,
                      const float* __restrict__ bmx, float* __restrict__ out) {
    int b = blockIdx.x >> 3, chunk = blockIdx.x & 7;
    int t = threadIdx.x;
    __shared__ float smn, smx;
    if (t < 64) {
        float mn = bmn[b * SPLITS + t];
        float mx = bmx[b * SPLITS + t];
        #pragma unroll
        for (int off = 32; off; off >>= 1) {
            mn = fminf(mn, __shfl_xor(mn, off));
            mx = fmaxf(mx, __shfl_xor(mx, off));
        }
        if (t == 0) { smn = mn; smx = mx; }
    }
    __syncthreads();
    float rmin = smn, inv = 1.f / (smx - smn);
    int i = chunk * 128 + t;
    float d = dvals[b * HW + i];
    float rn = (d - rmin) * inv;
    float z = (rn - 0.65f) * (1.f / 0.15f);
    out[b * HW + i] = 1.f / (1.f + expf(-z));
}

extern "C" void kernel_launch(void* const* d_in, const int* in_sizes, int n_in,
                              void* d_out, int out_size, void* d_ws, size_t ws_size,
                              hipStream_t stream) {
    const float* x      = (const float*)d_in[0];
    const float* conv_w = (const float*)d_in[1];
    const float* conv_b = (const float*)d_in[2];
    const float* q_w    = (const float*)d_in[3];
    // d_in[4] = q_b: per-batch constant -> cancels in min-max norm
    const float* k_w    = (const float*)d_in[5];
    const float* k_b    = (const float*)d_in[6];
    float* out = (float*)d_out;

    float* ws    = (float*)d_ws;
    float* xsum  = ws;                    // 8*512 = 4096
    float* t1g   = xsum + BATCH * CH;     // 4096
    float* t2g   = t1g + BATCH * CH;      // 4096
    float* wg    = t2g + BATCH * CH;      // 4096
    float* u     = wg  + BATCH * CH;      // 4096
    float* dvals = u   + BATCH * CH;      // 8192
    float* bmn   = dvals + BATCH * HW;    // 512
    float* bmx   = bmn + BATCH * SPLITS;  // 512

    hipLaunchKernelGGL(k_xsum,  dim3(128),           dim3(512), 0, stream, x, xsum);
    hipLaunchKernelGGL(k_t1,    dim3(1024),          dim3(256), 0, stream, xsum, conv_w, conv_b, t1g);
    hipLaunchKernelGGL(k_t2,    dim3(1024),          dim3(256), 0, stream, t1g, k_w, k_b, t2g);
    hipLaunchKernelGGL(k_wv,    dim3(64),            dim3(512), 0, stream, t2g, q_w, wg);
    hipLaunchKernelGGL(k_uv,    dim3(64),            dim3(512), 0, stream, wg, conv_w, u);
    hipLaunchKernelGGL(k_dpass, dim3(SPLITS, BATCH), dim3(256), 0, stream, x, u, dvals, bmn, bmx);
    hipLaunchKernelGGL(k_out,   dim3(64),            dim3(128), 0, stream, dvals, bmn, bmx, out);
}